// Round 1
// baseline (5341.148 us; speedup 1.0000x reference)
//
#include <hip/hip_runtime.h>
#include <hip/hip_bf16.h>
#include <math.h>

#define NN  1024   // spatial N = H*W
#define CCH 1024   // channels C
#define C8  128    // C/8
#define NB  32     // batch

// ---------------- reductions ----------------
__device__ __forceinline__ float wave_red_max(float v) {
#pragma unroll
  for (int o = 32; o > 0; o >>= 1) v = fmaxf(v, __shfl_down(v, o, 64));
  return v;
}
__device__ __forceinline__ float wave_red_sum(float v) {
#pragma unroll
  for (int o = 32; o > 0; o >>= 1) v += __shfl_down(v, o, 64);
  return v;
}
__device__ __forceinline__ float block_red_max(float v, float* red) {
  v = wave_red_max(v);
  if ((threadIdx.x & 63) == 0) red[threadIdx.x >> 6] = v;
  __syncthreads();
  v = fmaxf(fmaxf(red[0], red[1]), fmaxf(red[2], red[3]));
  __syncthreads();
  return v;
}
__device__ __forceinline__ float block_red_sum(float v, float* red) {
  v = wave_red_sum(v);
  if ((threadIdx.x & 63) == 0) red[threadIdx.x >> 6] = v;
  __syncthreads();
  v = red[0] + red[1] + red[2] + red[3];
  __syncthreads();
  return v;
}

// ---------------- shared GEMM inner ----------------
// BM=128 (rows, stride-16 per thread), BN=64 (cols, stride-16), BK=16.
// 256 threads: tx = tid&15 (cols), ty = tid>>4 (rows). acc[8][4] per thread.
// LDS reads are conflict-free: consecutive ty -> consecutive As addresses,
// consecutive tx -> consecutive Bs addresses.
__device__ __forceinline__ void gemm_inner(const float As[16][129], const float Bs[16][65],
                                           float acc[8][4], int tx, int ty) {
#pragma unroll
  for (int kk = 0; kk < 16; ++kk) {
    float a[8], bb[4];
#pragma unroll
    for (int r = 0; r < 8; ++r) a[r] = As[kk][ty + 16 * r];
#pragma unroll
    for (int c = 0; c < 4; ++c) bb[c] = Bs[kk][tx + 16 * c];
#pragma unroll
    for (int r = 0; r < 8; ++r)
#pragma unroll
      for (int c = 0; c < 4; ++c) acc[r][c] = fmaf(a[r], bb[c], acc[r][c]);
  }
}

// ---------------- kernel 1: Out[b][m][n] = sum_k A[m][k]*Bx[b][k][n] + bias[m] ----------------
// Used for q (A=Wq,Bx=x), k (A=Wk,Bx=y), v (A=Wv,Bx=z). Cols collapsed over (b,n).
__global__ __launch_bounds__(256) void k_gemm_wb(const float* __restrict__ A,
                                                 const float* __restrict__ Bx,
                                                 const float* __restrict__ bias,
                                                 float* __restrict__ Out, int M, int K) {
  __shared__ float As[16][129];
  __shared__ float Bs[16][65];
  const int tid = threadIdx.x, tx = tid & 15, ty = tid >> 4;
  const int m0 = blockIdx.x * 128;
  const int j0 = blockIdx.y * 64;
  const int b = j0 >> 10;
  const int n0 = j0 & 1023;
  const float* Bp = Bx + (size_t)b * K * NN;
  float acc[8][4];
#pragma unroll
  for (int r = 0; r < 8; ++r)
#pragma unroll
    for (int c = 0; c < 4; ++c) acc[r][c] = 0.f;

  for (int k0 = 0; k0 < K; k0 += 16) {
#pragma unroll
    for (int i = tid; i < 2048; i += 256) {  // A tile 128x16, store transposed
      int row = i >> 4, kk = i & 15;
      As[kk][row] = A[(size_t)(m0 + row) * K + (k0 + kk)];
    }
#pragma unroll
    for (int i = tid; i < 1024; i += 256) {  // B tile 16x64
      int kk = i >> 6, nn = i & 63;
      Bs[kk][nn] = Bp[(size_t)(k0 + kk) * NN + (n0 + nn)];
    }
    __syncthreads();
    gemm_inner(As, Bs, acc, tx, ty);
    __syncthreads();
  }
#pragma unroll
  for (int r = 0; r < 8; ++r) {
    const int m = m0 + ty + 16 * r;
    const float bv = bias[m];
#pragma unroll
    for (int c = 0; c < 4; ++c) {
      const int n = n0 + tx + 16 * c;
      Out[((size_t)b * M + m) * NN + n] = acc[r][c] + bv;
    }
  }
}

// ---------------- kernel 2: ec[b][i][j] = sum_c q[b][c][i]*k[b][c][j]  (TN) ----------------
__global__ __launch_bounds__(256) void k_gemm_ec(const float* __restrict__ q,
                                                 const float* __restrict__ kb,
                                                 float* __restrict__ Out) {
  __shared__ float As[16][129];
  __shared__ float Bs[16][65];
  const int tid = threadIdx.x, tx = tid & 15, ty = tid >> 4;
  const int i0 = blockIdx.x * 128, j0 = blockIdx.y * 64, b = blockIdx.z;
  const float* qp = q + (size_t)b * C8 * NN;
  const float* kp = kb + (size_t)b * C8 * NN;
  float acc[8][4];
#pragma unroll
  for (int r = 0; r < 8; ++r)
#pragma unroll
    for (int c = 0; c < 4; ++c) acc[r][c] = 0.f;

  for (int c0 = 0; c0 < C8; c0 += 16) {
#pragma unroll
    for (int i = tid; i < 2048; i += 256) {  // A tile: As[kk][ii] = q[c0+kk][i0+ii]
      int kk = i >> 7, ii = i & 127;
      As[kk][ii] = qp[(size_t)(c0 + kk) * NN + (i0 + ii)];
    }
#pragma unroll
    for (int i = tid; i < 1024; i += 256) {
      int kk = i >> 6, nn = i & 63;
      Bs[kk][nn] = kp[(size_t)(c0 + kk) * NN + (j0 + nn)];
    }
    __syncthreads();
    gemm_inner(As, Bs, acc, tx, ty);
    __syncthreads();
  }
#pragma unroll
  for (int r = 0; r < 8; ++r)
#pragma unroll
    for (int c = 0; c < 4; ++c)
      Out[(size_t)b * NN * NN + (size_t)(i0 + ty + 16 * r) * NN + (j0 + tx + 16 * c)] =
          acc[r][c];
}

// ---------------- kernel 3: es[b][m][d] = sum_n x[b][m][n]*y[b][d][n]  (NT) ----------------
__global__ __launch_bounds__(256) void k_gemm_es(const float* __restrict__ x,
                                                 const float* __restrict__ y,
                                                 float* __restrict__ Out) {
  __shared__ float As[16][129];
  __shared__ float Bs[16][65];
  const int tid = threadIdx.x, tx = tid & 15, ty = tid >> 4;
  const int m0 = blockIdx.x * 128, d0 = blockIdx.y * 64, b = blockIdx.z;
  const float* xp = x + (size_t)b * CCH * NN;
  const float* yp = y + (size_t)b * CCH * NN;
  float acc[8][4];
#pragma unroll
  for (int r = 0; r < 8; ++r)
#pragma unroll
    for (int c = 0; c < 4; ++c) acc[r][c] = 0.f;

  for (int k0 = 0; k0 < NN; k0 += 16) {
#pragma unroll
    for (int i = tid; i < 2048; i += 256) {
      int row = i >> 4, kk = i & 15;
      As[kk][row] = xp[(size_t)(m0 + row) * NN + (k0 + kk)];
    }
#pragma unroll
    for (int i = tid; i < 1024; i += 256) {  // Bs[kk][d] = y[d0+d][k0+kk]
      int d = i >> 4, kk = i & 15;
      Bs[kk][d] = yp[(size_t)(d0 + d) * NN + (k0 + kk)];
    }
    __syncthreads();
    gemm_inner(As, Bs, acc, tx, ty);
    __syncthreads();
  }
#pragma unroll
  for (int r = 0; r < 8; ++r)
#pragma unroll
    for (int c = 0; c < 4; ++c)
      Out[(size_t)b * NN * NN + (size_t)(m0 + ty + 16 * r) * NN + (d0 + tx + 16 * c)] =
          acc[r][c];
}

// ---------------- kernel 4: fused 3x softmax ----------------
// Row i of: ac = softmax(ec row); as = softmax(-es row)  [since softmax(max-e)==softmax(-e)];
// A = softmax(ac*as) -> overwrite ec row in place (block-local, race-free).
__global__ __launch_bounds__(256) void k_combine(float* __restrict__ ec,
                                                 const float* __restrict__ es) {
  __shared__ float red[4];
  const size_t row = blockIdx.x;
  float* cp = ec + row * NN;
  const float* sp = es + row * NN;
  const int tid = threadIdx.x;
  float4 c4 = reinterpret_cast<const float4*>(cp)[tid];
  float4 s4 = reinterpret_cast<const float4*>(sp)[tid];

  // softmax(ec)
  float mx = fmaxf(fmaxf(c4.x, c4.y), fmaxf(c4.z, c4.w));
  mx = block_red_max(mx, red);
  float e0 = __expf(c4.x - mx), e1 = __expf(c4.y - mx);
  float e2 = __expf(c4.z - mx), e3 = __expf(c4.w - mx);
  float sc = block_red_sum(e0 + e1 + e2 + e3, red);

  // softmax(-es)
  float t0 = -s4.x, t1 = -s4.y, t2 = -s4.z, t3 = -s4.w;
  float mt = fmaxf(fmaxf(t0, t1), fmaxf(t2, t3));
  mt = block_red_max(mt, red);
  float f0 = __expf(t0 - mt), f1 = __expf(t1 - mt);
  float f2 = __expf(t2 - mt), f3 = __expf(t3 - mt);
  float ss = block_red_sum(f0 + f1 + f2 + f3, red);

  // softmax(ac*as): products in [0,1] -> no max subtraction needed
  const float rc = 1.f / sc, rs = 1.f / ss;
  float g0 = __expf((e0 * rc) * (f0 * rs));
  float g1 = __expf((e1 * rc) * (f1 * rs));
  float g2 = __expf((e2 * rc) * (f2 * rs));
  float g3 = __expf((e3 * rc) * (f3 * rs));
  float s3 = block_red_sum(g0 + g1 + g2 + g3, red);
  const float r3 = 1.f / s3;
  float4 o;
  o.x = g0 * r3; o.y = g1 * r3; o.z = g2 * r3; o.w = g3 * r3;
  reinterpret_cast<float4*>(cp)[tid] = o;
}

// ---------------- kernel 5: Out[b][c][m] = z[b][c][m] + sum_n v[b][c][n]*At[b][m][n] ----------------
__global__ __launch_bounds__(256) void k_gemm_out(const float* __restrict__ v,
                                                  const float* __restrict__ At,
                                                  const float* __restrict__ z,
                                                  float* __restrict__ Out) {
  __shared__ float As[16][129];
  __shared__ float Bs[16][65];
  const int tid = threadIdx.x, tx = tid & 15, ty = tid >> 4;
  const int c0 = blockIdx.x * 128, m0 = blockIdx.y * 64, b = blockIdx.z;
  const float* vp = v + (size_t)b * CCH * NN;
  const float* ap = At + (size_t)b * NN * NN;
  float acc[8][4];
#pragma unroll
  for (int r = 0; r < 8; ++r)
#pragma unroll
    for (int c = 0; c < 4; ++c) acc[r][c] = 0.f;

  for (int k0 = 0; k0 < NN; k0 += 16) {
#pragma unroll
    for (int i = tid; i < 2048; i += 256) {
      int row = i >> 4, kk = i & 15;
      As[kk][row] = vp[(size_t)(c0 + row) * NN + (k0 + kk)];
    }
#pragma unroll
    for (int i = tid; i < 1024; i += 256) {  // Bs[kk][d] = At[m0+d][k0+kk]
      int d = i >> 4, kk = i & 15;
      Bs[kk][d] = ap[(size_t)(m0 + d) * NN + (k0 + kk)];
    }
    __syncthreads();
    gemm_inner(As, Bs, acc, tx, ty);
    __syncthreads();
  }
#pragma unroll
  for (int r = 0; r < 8; ++r)
#pragma unroll
    for (int c = 0; c < 4; ++c) {
      const size_t o = (size_t)b * CCH * NN + (size_t)(c0 + ty + 16 * r) * NN +
                       (m0 + tx + 16 * c);
      Out[o] = z[o] + acc[r][c];
    }
}

// ---------------- launch ----------------
extern "C" void kernel_launch(void* const* d_in, const int* in_sizes, int n_in,
                              void* d_out, int out_size, void* d_ws, size_t ws_size,
                              hipStream_t stream) {
  const float* z = (const float*)d_in[0];
  const float* x = (const float*)d_in[1];
  const float* y = (const float*)d_in[2];
  const float* Wq = (const float*)d_in[3];
  const float* bq = (const float*)d_in[4];
  const float* Wk = (const float*)d_in[5];
  const float* bk = (const float*)d_in[6];
  const float* Wv = (const float*)d_in[7];
  const float* bv = (const float*)d_in[8];
  float* out = (float*)d_out;

  // ws layout (fp32): q 16M | k 16M | ec 128M (-> attention in place) | es 128M (-> v in place)
  float* q = (float*)d_ws;
  float* kb = q + (size_t)NB * C8 * NN;
  float* ec = kb + (size_t)NB * C8 * NN;
  float* es = ec + (size_t)NB * NN * NN;

  dim3 blk(256);
  hipLaunchKernelGGL(k_gemm_wb, dim3(1, (NB * NN) / 64), blk, 0, stream, Wq, x, bq, q, C8, CCH);
  hipLaunchKernelGGL(k_gemm_wb, dim3(1, (NB * NN) / 64), blk, 0, stream, Wk, y, bk, kb, C8, CCH);
  hipLaunchKernelGGL(k_gemm_ec, dim3(8, 16, NB), blk, 0, stream, q, kb, ec);
  hipLaunchKernelGGL(k_gemm_es, dim3(8, 16, NB), blk, 0, stream, x, y, es);
  hipLaunchKernelGGL(k_combine, dim3(NB * NN), blk, 0, stream, ec, es);
  hipLaunchKernelGGL(k_gemm_wb, dim3(8, (NB * NN) / 64), blk, 0, stream, Wv, z, bv, es, CCH, CCH);
  hipLaunchKernelGGL(k_gemm_out, dim3(8, 16, NB), blk, 0, stream, es, ec, z, out);
}

// Round 3
// 885.690 us; speedup vs baseline: 6.0305x; 6.0305x over previous
//
#include <hip/hip_runtime.h>
#include <hip/hip_bf16.h>

typedef __attribute__((ext_vector_type(8))) short s8_t;    // 8 x bf16 (4 VGPR)
typedef __attribute__((ext_vector_type(4))) float f4_t;    // MFMA accumulator

// ---------- helpers ----------
__device__ __forceinline__ unsigned short f2bf(float f) {
  union { float f; unsigned u; } x; x.f = f;
  unsigned r = x.u + 0x7fffu + ((x.u >> 16) & 1u);  // RNE
  return (unsigned short)(r >> 16);
}

// split fp32 pair -> packed bf16 hi pair + packed bf16 lo pair (truncation split:
// hi = top16(x), lo = top16(x - hi); dropped residual <= 2^-16 |x|)
__device__ __forceinline__ void split2(float e0, float e1, unsigned& hp, unsigned& lp) {
  unsigned b0 = __float_as_uint(e0), b1 = __float_as_uint(e1);
  unsigned h0 = b0 & 0xFFFF0000u, h1 = b1 & 0xFFFF0000u;
  hp = (b0 >> 16) | h1;
  float l0 = e0 - __uint_as_float(h0), l1 = e1 - __uint_as_float(h1);
  lp = (__float_as_uint(l0) >> 16) | (__float_as_uint(l1) & 0xFFFF0000u);
}

__device__ __forceinline__ void gload16(const void* g, void* l) {
  __builtin_amdgcn_global_load_lds(
      (const __attribute__((address_space(1))) void*)g,
      (__attribute__((address_space(3))) void*)l, 16, 0, 0);
}

// ---------- fp32 -> bf16 elementwise convert (for Wv) ----------
__global__ __launch_bounds__(256) void k_convert(const float* __restrict__ in,
                                                 unsigned short* __restrict__ out, int n) {
  int i = (blockIdx.x * 256 + threadIdx.x) * 8;
  if (i >= n) return;
  float4 a = *(const float4*)(in + i);
  float4 b = *(const float4*)(in + i + 4);
  ushort4 u0; u0.x = f2bf(a.x); u0.y = f2bf(a.y); u0.z = f2bf(a.z); u0.w = f2bf(a.w);
  ushort4 u1; u1.x = f2bf(b.x); u1.y = f2bf(b.y); u1.z = f2bf(b.z); u1.w = f2bf(b.w);
  *(ushort4*)(out + i) = u0;
  *(ushort4*)(out + i + 4) = u1;
}

// ---------- fp32 [1024][1024]/batch -> fp32 transposed ----------
__global__ __launch_bounds__(256) void k_transp32(const float* __restrict__ in,
                                                  float* __restrict__ out) {
  __shared__ float tile[64][65];
  const int t = threadIdx.x, b = blockIdx.z;
  const int r0 = blockIdx.y * 64, c0 = blockIdx.x * 64;
  const float* ip = in + (size_t)b * 1048576;
  float* op = out + (size_t)b * 1048576;
  const int tr = t >> 4, tc = (t & 15) * 4;
#pragma unroll
  for (int p = 0; p < 4; ++p) {
    int r = p * 16 + tr;
    float4 v = *(const float4*)(ip + (size_t)(r0 + r) * 1024 + c0 + tc);
    tile[r][tc] = v.x; tile[r][tc + 1] = v.y; tile[r][tc + 2] = v.z; tile[r][tc + 3] = v.w;
  }
  __syncthreads();
#pragma unroll
  for (int p = 0; p < 4; ++p) {
    int n = p * 16 + tr;
    float4 w;
    w.x = tile[tc][n]; w.y = tile[tc + 1][n]; w.z = tile[tc + 2][n]; w.w = tile[tc + 3][n];
    *(float4*)(op + (size_t)(c0 + n) * 1024 + r0 + tc) = w;
  }
}

// ---------- fp32 [1024][1024]/batch -> bf16 transposed (for z) ----------
__global__ __launch_bounds__(256) void k_transpbf(const float* __restrict__ in,
                                                  unsigned short* __restrict__ outt) {
  __shared__ unsigned short tile[64][72];
  const int t = threadIdx.x, b = blockIdx.z;
  const int r0 = blockIdx.y * 64, c0 = blockIdx.x * 64;
  const float* ip = in + (size_t)b * 1048576;
  const int tr = t >> 4, tc = (t & 15) * 4;
#pragma unroll
  for (int p = 0; p < 4; ++p) {
    int r = p * 16 + tr;
    float4 v = *(const float4*)(ip + (size_t)(r0 + r) * 1024 + c0 + tc);
    tile[r][tc] = f2bf(v.x); tile[r][tc + 1] = f2bf(v.y);
    tile[r][tc + 2] = f2bf(v.z); tile[r][tc + 3] = f2bf(v.w);
  }
  __syncthreads();
#pragma unroll
  for (int p = 0; p < 4; ++p) {
    int n = p * 16 + tr;
    ushort4 w;
    w.x = tile[tc][n]; w.y = tile[tc + 1][n]; w.z = tile[tc + 2][n]; w.w = tile[tc + 3][n];
    *(ushort4*)(outt + (size_t)b * 1048576 + (size_t)(c0 + n) * 1024 + r0 + tc) = w;
  }
}

// ---------- split-bf16 3-term MFMA GEMM, fp32 operands ----------
// C[m][n] = sum_k A[m][k]*B[n][k], A,B fp32 K-contiguous; fp32-grade accuracy via
// hi/lo split: acc += Ah*Bh + Ah*Bl + Al*Bh. 128x128 tile, BK=32, 4 waves.
// BIAS_MODE: 0 none, 2 bias[col]. Output fp32.
template <int BIAS_MODE>
__global__ __launch_bounds__(256) void k_mfma3(
    const float* __restrict__ A, int lda, long long sA,
    const float* __restrict__ B, int ldb, long long sB,
    float* __restrict__ C, int ldc, long long sC,
    const float* __restrict__ bias, int K) {
  __shared__ __align__(16) unsigned short Ah[4096], Al[4096], Bh[4096], Bl[4096];
  const int tid = threadIdx.x;
  const int lane = tid & 63, wave = tid >> 6;
  const int wr = wave >> 1, wc = wave & 1;
  const int bz = blockIdx.z;
  const int m0 = blockIdx.x * 128, n0 = blockIdx.y * 128;

  // staging: thread t covers row t>>1, k-cols [(t&1)*16, +16)
  const int sr = tid >> 1, sh = (tid & 1) * 16;
  const float* ag = A + (long long)bz * sA + (long long)(m0 + sr) * lda + sh;
  const float* bg = B + (long long)bz * sB + (long long)(n0 + sr) * ldb + sh;
  unsigned short* wah = &Ah[sr * 32 + sh];
  unsigned short* wal = &Al[sr * 32 + sh];
  unsigned short* wbh = &Bh[sr * 32 + sh];
  unsigned short* wbl = &Bl[sr * 32 + sh];

  const int lr = lane & 15, lg = lane >> 4;
  const int fa = (wr * 64 + lr) * 32 + lg * 8;  // + f*512 per 16-row block
  const int fb = (wc * 64 + lr) * 32 + lg * 8;

  f4_t acc[4][4];
#pragma unroll
  for (int i = 0; i < 4; ++i)
#pragma unroll
    for (int j = 0; j < 4; ++j) acc[i][j] = (f4_t)0.f;

  for (int k0 = 0; k0 < K; k0 += 32) {
    // ---- stage: load fp32, split, write 4 LDS planes ----
    float av[16], bv[16];
#pragma unroll
    for (int p = 0; p < 4; ++p) {
      *(float4*)(av + p * 4) = *(const float4*)(ag + p * 4);
      *(float4*)(bv + p * 4) = *(const float4*)(bg + p * 4);
    }
    unsigned ah[8], al[8], bh[8], bl[8];
#pragma unroll
    for (int p = 0; p < 8; ++p) {
      split2(av[2 * p], av[2 * p + 1], ah[p], al[p]);
      split2(bv[2 * p], bv[2 * p + 1], bh[p], bl[p]);
    }
    *(uint4*)(wah) = *(uint4*)(ah);     *(uint4*)(wah + 8) = *(uint4*)(ah + 4);
    *(uint4*)(wal) = *(uint4*)(al);     *(uint4*)(wal + 8) = *(uint4*)(al + 4);
    *(uint4*)(wbh) = *(uint4*)(bh);     *(uint4*)(wbh + 8) = *(uint4*)(bh + 4);
    *(uint4*)(wbl) = *(uint4*)(bl);     *(uint4*)(wbl + 8) = *(uint4*)(bl + 4);
    ag += 32; bg += 32;
    __syncthreads();

    // ---- fragments + 48 MFMA (3 terms x 16) ----
    s8_t fah[4], fbh[4], ftmp[4];
#pragma unroll
    for (int f = 0; f < 4; ++f) {
      fah[f] = *(const s8_t*)(Ah + fa + f * 512);
      fbh[f] = *(const s8_t*)(Bh + fb + f * 512);
    }
#pragma unroll
    for (int i = 0; i < 4; ++i)
#pragma unroll
      for (int j = 0; j < 4; ++j)
        acc[i][j] = __builtin_amdgcn_mfma_f32_16x16x32_bf16(fah[i], fbh[j], acc[i][j], 0, 0, 0);
#pragma unroll
    for (int f = 0; f < 4; ++f) ftmp[f] = *(const s8_t*)(Bl + fb + f * 512);
#pragma unroll
    for (int i = 0; i < 4; ++i)
#pragma unroll
      for (int j = 0; j < 4; ++j)
        acc[i][j] = __builtin_amdgcn_mfma_f32_16x16x32_bf16(fah[i], ftmp[j], acc[i][j], 0, 0, 0);
#pragma unroll
    for (int f = 0; f < 4; ++f) ftmp[f] = *(const s8_t*)(Al + fa + f * 512);
#pragma unroll
    for (int i = 0; i < 4; ++i)
#pragma unroll
      for (int j = 0; j < 4; ++j)
        acc[i][j] = __builtin_amdgcn_mfma_f32_16x16x32_bf16(ftmp[i], fbh[j], acc[i][j], 0, 0, 0);
    __syncthreads();
  }

  // epilogue: C/D layout col=lane&15, row=(lane>>4)*4+e
#pragma unroll
  for (int i = 0; i < 4; ++i) {
    const int rbase = m0 + wr * 64 + i * 16 + lg * 4;
#pragma unroll
    for (int j = 0; j < 4; ++j) {
      const int col = n0 + wc * 64 + j * 16 + lr;
      float bc = (BIAS_MODE == 2) ? bias[col] : 0.f;
#pragma unroll
      for (int e = 0; e < 4; ++e) {
        float v = acc[i][j][e];
        if (BIAS_MODE == 2) v += bc;
        C[(long long)bz * sC + (long long)(rbase + e) * ldc + col] = v;
      }
    }
  }
}

// ---------- bf16 NT MFMA GEMM (gload_lds path) for v and out ----------
// BIAS_MODE: 0 none, 1 bias[row]. RESID: C = resid + acc (fp32 out); else bf16 out.
template <int BIAS_MODE, bool OUT_BF16, bool RESID>
__global__ __launch_bounds__(256) void k_mfma(
    const unsigned short* __restrict__ A, int lda, long long sA,
    const unsigned short* __restrict__ B, int ldb, long long sB,
    void* __restrict__ Cp, int ldc, long long sC,
    const float* __restrict__ bias,
    const float* __restrict__ resid, long long sR, int K) {
  __shared__ __align__(16) unsigned short As[4096];
  __shared__ __align__(16) unsigned short Bs[4096];
  const int tid = threadIdx.x;
  const int lane = tid & 63, wave = tid >> 6;
  const int wr = wave >> 1, wc = wave & 1;
  const int bz = blockIdx.z;
  const int m0 = blockIdx.x * 128, n0 = blockIdx.y * 128;

  const int ch0 = wave * 64 + lane, ch1 = ch0 + 256;
  const unsigned short* pa0 = A + (long long)bz * sA + (long long)(m0 + (ch0 >> 2)) * lda + (ch0 & 3) * 8;
  const unsigned short* pa1 = A + (long long)bz * sA + (long long)(m0 + (ch1 >> 2)) * lda + (ch1 & 3) * 8;
  const unsigned short* pb0 = B + (long long)bz * sB + (long long)(n0 + (ch0 >> 2)) * ldb + (ch0 & 3) * 8;
  const unsigned short* pb1 = B + (long long)bz * sB + (long long)(n0 + (ch1 >> 2)) * ldb + (ch1 & 3) * 8;
  char* la0 = (char*)As + wave * 1024;
  char* la1 = la0 + 4096;
  char* lb0 = (char*)Bs + wave * 1024;
  char* lb1 = lb0 + 4096;

  const int lr = lane & 15, lg = lane >> 4;
  const unsigned short* arp = As + (wr * 64 + lr) * 32 + lg * 8;
  const unsigned short* brp = Bs + (wc * 64 + lr) * 32 + lg * 8;

  f4_t acc[4][4];
#pragma unroll
  for (int i = 0; i < 4; ++i)
#pragma unroll
    for (int j = 0; j < 4; ++j) acc[i][j] = (f4_t)0.f;

  for (int k0 = 0; k0 < K; k0 += 32) {
    gload16(pa0, la0); gload16(pa1, la1);
    gload16(pb0, lb0); gload16(pb1, lb1);
    pa0 += 32; pa1 += 32; pb0 += 32; pb1 += 32;
    __syncthreads();
    s8_t af[4], bf[4];
#pragma unroll
    for (int f = 0; f < 4; ++f) {
      af[f] = *(const s8_t*)(arp + f * 16 * 32);
      bf[f] = *(const s8_t*)(brp + f * 16 * 32);
    }
#pragma unroll
    for (int i = 0; i < 4; ++i)
#pragma unroll
      for (int j = 0; j < 4; ++j)
        acc[i][j] = __builtin_amdgcn_mfma_f32_16x16x32_bf16(af[i], bf[j], acc[i][j], 0, 0, 0);
    __syncthreads();
  }

#pragma unroll
  for (int i = 0; i < 4; ++i) {
    const int rbase = m0 + wr * 64 + i * 16 + lg * 4;
#pragma unroll
    for (int j = 0; j < 4; ++j) {
      const int col = n0 + wc * 64 + j * 16 + lr;
#pragma unroll
      for (int e = 0; e < 4; ++e) {
        const int row = rbase + e;
        float v = acc[i][j][e];
        if (BIAS_MODE == 1) v += bias[row];
        const long long off = (long long)bz * sC + (long long)row * ldc + col;
        if (RESID) v += resid[(long long)bz * sR + (long long)row * ldc + col];
        if (OUT_BF16) ((unsigned short*)Cp)[off] = f2bf(v);
        else          ((float*)Cp)[off] = v;
      }
    }
  }
}

// ---------- fused triple softmax ----------
__device__ __forceinline__ float wave_red_max(float v) {
#pragma unroll
  for (int o = 32; o > 0; o >>= 1) v = fmaxf(v, __shfl_down(v, o, 64));
  return v;
}
__device__ __forceinline__ float wave_red_sum(float v) {
#pragma unroll
  for (int o = 32; o > 0; o >>= 1) v += __shfl_down(v, o, 64);
  return v;
}
__device__ __forceinline__ float block_red_max(float v, float* red) {
  v = wave_red_max(v);
  if ((threadIdx.x & 63) == 0) red[threadIdx.x >> 6] = v;
  __syncthreads();
  v = fmaxf(fmaxf(red[0], red[1]), fmaxf(red[2], red[3]));
  __syncthreads();
  return v;
}
__device__ __forceinline__ float block_red_sum(float v, float* red) {
  v = wave_red_sum(v);
  if ((threadIdx.x & 63) == 0) red[threadIdx.x >> 6] = v;
  __syncthreads();
  v = red[0] + red[1] + red[2] + red[3];
  __syncthreads();
  return v;
}

// per row: ac = softmax(ec); as = softmax(-es); attn = softmax(ac*as) -> bf16
// into first 2KB of own ec row (block-local in-place; all reads precede writes
// across multiple __syncthreads).
__global__ __launch_bounds__(256) void k_combine(float* __restrict__ ec,
                                                 const float* __restrict__ es) {
  __shared__ float red[4];
  const size_t row = blockIdx.x;
  float* cp = ec + row * 1024;
  const float* sp = es + row * 1024;
  const int tid = threadIdx.x;
  float4 c4 = ((const float4*)cp)[tid];
  float4 s4 = ((const float4*)sp)[tid];

  float mx = fmaxf(fmaxf(c4.x, c4.y), fmaxf(c4.z, c4.w));
  mx = block_red_max(mx, red);
  float e0 = __expf(c4.x - mx), e1 = __expf(c4.y - mx);
  float e2 = __expf(c4.z - mx), e3 = __expf(c4.w - mx);
  float sc = block_red_sum(e0 + e1 + e2 + e3, red);

  float t0 = -s4.x, t1 = -s4.y, t2 = -s4.z, t3 = -s4.w;
  float mt = fmaxf(fmaxf(t0, t1), fmaxf(t2, t3));
  mt = block_red_max(mt, red);
  float f0 = __expf(t0 - mt), f1 = __expf(t1 - mt);
  float f2 = __expf(t2 - mt), f3 = __expf(t3 - mt);
  float ss = block_red_sum(f0 + f1 + f2 + f3, red);

  const float rc = 1.f / sc, rs = 1.f / ss;
  float g0 = __expf((e0 * rc) * (f0 * rs));
  float g1 = __expf((e1 * rc) * (f1 * rs));
  float g2 = __expf((e2 * rc) * (f2 * rs));
  float g3 = __expf((e3 * rc) * (f3 * rs));
  float s3 = block_red_sum(g0 + g1 + g2 + g3, red);
  const float r3 = 1.f / s3;
  ushort4 o;
  o.x = f2bf(g0 * r3); o.y = f2bf(g1 * r3); o.z = f2bf(g2 * r3); o.w = f2bf(g3 * r3);
  ((ushort4*)cp)[tid] = o;
}

// ---------- launch ----------
extern "C" void kernel_launch(void* const* d_in, const int* in_sizes, int n_in,
                              void* d_out, int out_size, void* d_ws, size_t ws_size,
                              hipStream_t stream) {
  const float* z = (const float*)d_in[0];
  const float* x = (const float*)d_in[1];
  const float* y = (const float*)d_in[2];
  const float* Wq = (const float*)d_in[3];
  const float* bq = (const float*)d_in[4];
  const float* Wk = (const float*)d_in[5];
  const float* bk = (const float*)d_in[6];
  const float* Wv = (const float*)d_in[7];
  const float* bv = (const float*)d_in[8];
  float* out = (float*)d_out;

  // ws (288 MiB exact, proven available in round 1):
  // P01 [0,128M):   es fp32           -> after combine: z_t bf16 [0,64M) | v_bf [64M,128M)
  // P23 [128,256M): x_tf32 -> y_tf32 -> ec fp32 (attn bf16 in-place, row stride 2048)
  // P4  [256,288M): q_t fp32 16M | k_t fp32 16M -> after ec: wv bf16 2M
  char* ws = (char*)d_ws;
  float* es = (float*)ws;
  unsigned short* z_t = (unsigned short*)ws;
  unsigned short* v_bf = z_t + 33554432;
  char* wsB = ws + 134217728;
  float* xytf = (float*)wsB;           // x_tf32 then y_tf32
  float* ec = (float*)wsB;
  unsigned short* attn = (unsigned short*)wsB;
  char* wsC = ws + 268435456;
  float* q_t = (float*)wsC;            // [32][1024][128]
  float* k_t = q_t + 4194304;
  unsigned short* wv = (unsigned short*)wsC;

  dim3 blk(256);
  // x^T fp32 ; q_t[b][n][o] = x_t[n][:] . Wq[o][:] + bq[o]
  hipLaunchKernelGGL(k_transp32, dim3(16, 16, 32), blk, 0, stream, x, xytf);
  hipLaunchKernelGGL((k_mfma3<2>), dim3(8, 1, 32), blk, 0, stream,
                     xytf, 1024, 1048576LL, Wq, 1024, 0LL, q_t, 128, 131072LL, bq, 1024);
  // y^T fp32 ; k_t
  hipLaunchKernelGGL(k_transp32, dim3(16, 16, 32), blk, 0, stream, y, xytf);
  hipLaunchKernelGGL((k_mfma3<2>), dim3(8, 1, 32), blk, 0, stream,
                     xytf, 1024, 1048576LL, Wk, 1024, 0LL, k_t, 128, 131072LL, bk, 1024);
  // es[b][m][d] = x[m][:] . y[d][:]   (fp32 operands straight from d_in)
  hipLaunchKernelGGL((k_mfma3<0>), dim3(8, 8, 32), blk, 0, stream,
                     x, 1024, 1048576LL, y, 1024, 1048576LL, es, 1024, 1048576LL,
                     (const float*)nullptr, 1024);
  // ec[b][i][j] = q_t[i][:] . k_t[j][:]  (K=128) -> P23 (y_tf dead)
  hipLaunchKernelGGL((k_mfma3<0>), dim3(8, 8, 32), blk, 0, stream,
                     q_t, 128, 131072LL, k_t, 128, 131072LL, ec, 1024, 1048576LL,
                     (const float*)nullptr, 128);
  // triple softmax -> attn bf16 in-place in ec rows
  hipLaunchKernelGGL(k_combine, dim3(32768), blk, 0, stream, ec, es);
  // z^T bf16 -> P01 low (es dead) ; Wv bf16 -> P4 (q_t,k_t dead)
  hipLaunchKernelGGL(k_transpbf, dim3(16, 16, 32), blk, 0, stream, z, z_t);
  hipLaunchKernelGGL(k_convert, dim3(512), blk, 0, stream, Wv, wv, 1048576);
  // v[b][o][n] = Wv[o][:] . z_t[n][:] + bv[o] -> bf16
  hipLaunchKernelGGL((k_mfma<1, true, false>), dim3(8, 8, 32), blk, 0, stream,
                     wv, 1024, 0LL, z_t, 1024, 1048576LL, (void*)v_bf, 1024, 1048576LL,
                     bv, (const float*)nullptr, 0LL, 1024);
  // out[b][c][m] = z[b][c][m] + v[c][:] . attn[m][:]
  hipLaunchKernelGGL((k_mfma<0, false, true>), dim3(8, 8, 32), blk, 0, stream,
                     v_bf, 1024, 1048576LL, attn, 2048, 2097152LL, (void*)out, 1024, 1048576LL,
                     (const float*)nullptr, z, 1048576LL, 1024);
}